// Round 3
// baseline (10347.681 us; speedup 1.0000x reference)
//
#include <hip/hip_runtime.h>
#include <stdint.h>

typedef short short8 __attribute__((ext_vector_type(8)));
typedef float f32x4 __attribute__((ext_vector_type(4)));
typedef unsigned short ushort_t;

constexpr int Bsz  = 4096;
constexpr int Tst  = 20;
constexpr int Fin  = 2000;
constexpr int H1   = 512;
constexpr int H2   = 128;
constexpr int NOUT = 10;
constexpr int FW   = 64;     // words per spike row (2048 bits)

constexpr int C1_ROWS = 5120;   // layer-1 chunk rows (256 batches)
constexpr int C2_ROWS = 20480;  // layer-2 chunk rows (1024 batches)

// ---------------- Threefry-2x32-20, key = jax.random.key(1) = [0,1] ----------------
__device__ __forceinline__ void tf2x32(uint32_t c0, uint32_t c1, uint32_t& o0, uint32_t& o1) {
  const uint32_t k0 = 0u, k1 = 1u, k2 = 0x1BD11BDBu;
  uint32_t x0 = c0 + k0;
  uint32_t x1 = c1 + k1;
#define ROTL(x,d) (((x)<<(d))|((x)>>(32-(d))))
#define RND(r) { x0 += x1; x1 = ROTL(x1,(r)) ^ x0; }
  RND(13) RND(15) RND(26) RND(6)   x0 += k1; x1 += k2 + 1u;
  RND(17) RND(29) RND(16) RND(24)  x0 += k2; x1 += k0 + 2u;
  RND(13) RND(15) RND(26) RND(6)   x0 += k0; x1 += k1 + 3u;
  RND(17) RND(29) RND(16) RND(24)  x0 += k1; x1 += k2 + 4u;
  RND(13) RND(15) RND(26) RND(6)   x0 += k2; x1 += k0 + 5u;
#undef RND
#undef ROTL
  o0 = x0; o1 = x1;
}

// Partitionable threefry: counter = (0, flat_idx), bits = o0^o1.
__global__ void spikegen(const float* __restrict__ x, uint32_t* __restrict__ sbits) {
  int gid = blockIdx.x * blockDim.x + threadIdx.x;  // Bsz*Tst*FW threads
  if (gid >= Bsz * Tst * FW) return;
  int w = gid & 63;
  int row = gid >> 6;                 // b*T + t
  int b = row / Tst;
  uint32_t bits = 0;
  int fbase = w * 32;
  const float* xr = x + (size_t)b * Fin;
  uint32_t ibase = (uint32_t)row * (uint32_t)Fin;
  for (int j = 0; j < 32; ++j) {
    int f = fbase + j;
    if (f >= Fin) break;
    uint32_t o0, o1;
    tf2x32(0u, ibase + (uint32_t)f, o0, o1);
    uint32_t m = o0 ^ o1;
    float u = __uint_as_float((m >> 9) | 0x3f800000u) - 1.0f;
    if (u < xr[f]) bits |= (1u << j);
  }
  sbits[(size_t)row * FW + w] = bits;
}

// Decompose W[o][f] (f32) into 5 balanced base-256 digit slices on grid 2^-42.
// Bsl[s][o][f] (bf16) = d_s * 2^(8s-42), exact in bf16.
__global__ void wslice(const float* __restrict__ W, int O, int K, int KPAD,
                       ushort_t* __restrict__ Bsl) {
  int idx = blockIdx.x * 256 + threadIdx.x;
  if (idx >= O * KPAD) return;
  int o = idx / KPAD, f = idx % KPAD;
  long long wi = 0;
  if (f < K) {
    double w = (double)W[(size_t)o * K + f];
    wi = llround(w * 4398046511104.0);  // 2^42
  }
#pragma unroll
  for (int s = 0; s < 5; ++s) {
    int d;
    if (s < 4) { d = (int)(int8_t)(wi & 0xff); wi = (wi - d) >> 8; }
    else d = (int)wi;
    float val = ldexpf((float)d, 8 * s - 42);
    uint32_t u = __float_as_uint(val);
    Bsl[((size_t)s * O + o) * KPAD + f] = (ushort_t)(u >> 16);  // exact bf16
  }
}

// Expand packed spike bits -> bf16 0/1 matrix [rows][KPAD] for one chunk.
__global__ void expand_bits(const uint32_t* __restrict__ bits, int AW, int rowBase,
                            int KPAD, int rows, ushort_t* __restrict__ Abf) {
  int nb = KPAD / 8;  // bytes per row
  int gid = blockIdx.x * 256 + threadIdx.x;
  if (gid >= rows * nb) return;
  int r = gid / nb, bi = gid % nb;
  uint32_t word = bits[(size_t)(rowBase + r) * AW + (bi >> 2)];
  uint32_t byte = (word >> ((bi & 3) * 8)) & 0xff;
  uint4 v;
  uint32_t d[4];
#pragma unroll
  for (int j = 0; j < 4; ++j)
    d[j] = (((byte >> (2 * j)) & 1u) ? 0x3f80u : 0u) |
           (((byte >> (2 * j + 1)) & 1u) ? 0x3f800000u : 0u);
  v.x = d[0]; v.y = d[1]; v.z = d[2]; v.w = d[3];
  ((uint4*)Abf)[gid] = v;
}

// ---------------- MFMA slice GEMM ----------------
typedef const __attribute__((address_space(1))) uint32_t* gas_ptr;
typedef __attribute__((address_space(3))) uint32_t* las_ptr;

__device__ __forceinline__ void gld16(const void* g, void* l) {
  __builtin_amdgcn_global_load_lds((gas_ptr)g, (las_ptr)l, 16, 0, 0);
}

__device__ __forceinline__ short8 bc8(uint4 v) { return __builtin_bit_cast(short8, v); }

// C[r][col] = sum_f A[r][f]*W[col][f] + bias[col], exact via 5 bf16 slices.
// Block: 320 threads = 5 waves (wave = slice). Tile 64x64, per-wave 4x4 16x16x32 MFMAs.
template <int O, int KPAD>
__global__ __launch_bounds__(320) void gemm5(
    const ushort_t* __restrict__ Abf,   // [rows][KPAD] bf16 0/1
    const ushort_t* __restrict__ Bsl,   // [5][O][KPAD] bf16 slices
    const float* __restrict__ bias,
    double* __restrict__ C) {           // [rows][O]
  constexpr int NSTEP = KPAD / 32;
  __shared__ __align__(16) char smem[40960];
  uint4* sA = (uint4*)smem;  // [2][4 fq][64 row] of 16B
  const int tid = threadIdx.x;
  const int lane = tid & 63, wid = tid >> 6;
  const int row0 = blockIdx.x * 64, col0 = blockIdx.y * 64;

  const ushort_t* pA = Abf + (size_t)(row0 + lane) * KPAD + wid * 8;  // used for wid<4
  const ushort_t* pB = Bsl + ((size_t)wid * O + col0 + (lane & 15)) * KPAD + (lane >> 4) * 8;

  f32x4 acc[4][4];
#pragma unroll
  for (int m = 0; m < 4; ++m)
#pragma unroll
    for (int n = 0; n < 4; ++n) acc[m][n] = f32x4{0.f, 0.f, 0.f, 0.f};

  uint4 B0[4], B1[4];

#define STAGE_A(buf, st) do { if (wid < 4) gld16(pA + (st) * 32, sA + (buf) * 256 + wid * 64); } while (0)
#define LOAD_B(reg, st) do { _Pragma("unroll") \
    for (int n = 0; n < 4; ++n) reg[n] = *(const uint4*)(pB + (st) * 32 + n * 16 * KPAD); } while (0)

  STAGE_A(0, 0);
  LOAD_B(B0, 0);
  __syncthreads();

#define BODY(st, Bcur, Bnxt) do {                                              \
    if ((st) + 1 < NSTEP) { STAGE_A(((st) + 1) & 1, (st) + 1); LOAD_B(Bnxt, (st) + 1); } \
    const uint4* sa = sA + ((st) & 1) * 256 + (lane >> 4) * 64 + (lane & 15);  \
    uint4 a0 = sa[0], a1 = sa[16], a2 = sa[32], a3 = sa[48];                   \
    short8 av0 = bc8(a0), av1 = bc8(a1), av2 = bc8(a2), av3 = bc8(a3);         \
    _Pragma("unroll")                                                          \
    for (int n = 0; n < 4; ++n) {                                              \
      short8 bv = bc8(Bcur[n]);                                                \
      acc[0][n] = __builtin_amdgcn_mfma_f32_16x16x32_bf16(av0, bv, acc[0][n], 0, 0, 0); \
      acc[1][n] = __builtin_amdgcn_mfma_f32_16x16x32_bf16(av1, bv, acc[1][n], 0, 0, 0); \
      acc[2][n] = __builtin_amdgcn_mfma_f32_16x16x32_bf16(av2, bv, acc[2][n], 0, 0, 0); \
      acc[3][n] = __builtin_amdgcn_mfma_f32_16x16x32_bf16(av3, bv, acc[3][n], 0, 0, 0); \
    }                                                                          \
    __syncthreads();                                                           \
  } while (0)

#pragma unroll 1
  for (int st = 0; st < NSTEP; st += 2) {
    BODY(st, B0, B1);
    BODY(st + 1, B1, B0);
  }
#undef BODY
#undef LOAD_B
#undef STAGE_A

  // Epilogue: combine 5 slices (one per wave) exactly in f64, in 2 column phases.
  float* red = (float*)smem;  // [5][64][32]
#pragma unroll 1
  for (int p = 0; p < 2; ++p) {
    __syncthreads();
#pragma unroll
    for (int n2 = 0; n2 < 2; ++n2) {
      int n = 2 * p + n2;
#pragma unroll
      for (int m = 0; m < 4; ++m)
#pragma unroll
        for (int r = 0; r < 4; ++r) {
          int row = m * 16 + (lane >> 4) * 4 + r;
          red[(wid * 64 + row) * 32 + n2 * 16 + (lane & 15)] = acc[m][n][r];
        }
    }
    __syncthreads();
    for (int e = tid; e < 2048; e += 320) {
      int row = e >> 5, cc = e & 31;
      double s = 0.0;
#pragma unroll
      for (int sl = 0; sl < 5; ++sl) s += (double)red[(sl * 64 + row) * 32 + cc];
      int col = col0 + p * 32 + cc;
      C[(size_t)(row0 + row) * O + col] = s + (double)bias[col];
    }
  }
}

// LIF layer 1 over T steps, one block per batch row of this chunk (512 thr = H1).
__global__ __launch_bounds__(512) void lif1(const double* __restrict__ inp1,
                                            uint32_t* __restrict__ spk1, int bBase) {
  int b_local = blockIdx.x;
  int o = threadIdx.x;
  int b = bBase + b_local;
  double mem = 0.0;
  for (int t = 0; t < Tst; ++t) {
    double inp = inp1[((size_t)(b_local * Tst + t)) * H1 + o];
    mem = mem + (inp - mem) / 2.0;
    bool spk = (mem >= 1.0);
    unsigned long long m = __ballot(spk);
    if ((o & 63) == 0) {
      int wv = o >> 6;
      size_t base = ((size_t)(b * Tst + t)) * (H1 / 32);
      spk1[base + wv * 2]     = (uint32_t)(m & 0xffffffffu);
      spk1[base + wv * 2 + 1] = (uint32_t)(m >> 32);
    }
    if (spk) mem = 0.0;
  }
}

// LIF layer 2: one block per batch row of this chunk, write final membrane.
__global__ __launch_bounds__(128) void lif2(const double* __restrict__ inp2,
                                            double* __restrict__ mem2, int bBase) {
  int b_local = blockIdx.x;
  int o = threadIdx.x;
  double mem = 0.0;
  for (int t = 0; t < Tst; ++t) {
    double inp = inp2[((size_t)(b_local * Tst + t)) * H2 + o];
    mem = mem + (inp - mem) / 2.0;
    if (mem >= 1.0) mem = 0.0;
  }
  mem2[(size_t)(bBase + b_local) * H2 + o] = mem;
}

// out = mem2 @ Wd^T + bd
__global__ void finalk(const double* __restrict__ mem2, const float* __restrict__ Wd,
                       const float* __restrict__ bd, float* __restrict__ out) {
  int gid = blockIdx.x * blockDim.x + threadIdx.x;
  if (gid >= Bsz * NOUT) return;
  int b = gid / NOUT, j = gid % NOUT;
  double s = (double)bd[j];
  const double* m = mem2 + (size_t)b * H2;
  const float* wr = Wd + (size_t)j * H2;
  for (int k = 0; k < H2; ++k) s = fma(m[k], (double)wr[k], s);
  out[gid] = (float)s;
}

extern "C" void kernel_launch(void* const* d_in, const int* in_sizes, int n_in,
                              void* d_out, int out_size, void* d_ws, size_t ws_size,
                              hipStream_t stream) {
  const float* x  = (const float*)d_in[0];
  const float* W1 = (const float*)d_in[1];
  const float* b1 = (const float*)d_in[2];
  const float* W2 = (const float*)d_in[3];
  const float* b2 = (const float*)d_in[4];
  const float* Wd = (const float*)d_in[5];
  const float* bd = (const float*)d_in[6];
  float* out = (float*)d_out;

  char* ws = (char*)d_ws;
  // Layout (bytes):
  ushort_t* Abf   = (ushort_t*)(ws);                         // 20,971,520 (chunk A bf16, reused)
  double*   inp   = (double*)  (ws + 20971520ull);           // 20,971,520 (chunk inp f64, reused)
  double*   mem2  = (double*)  (ws + 41943040ull);           //  4,194,304
  uint32_t* sbits = (uint32_t*)(ws + 46137344ull);           // 20,971,520
  uint32_t* spk1  = (uint32_t*)(ws + 67108864ull);           //  5,242,880
  ushort_t* Bsl1  = (ushort_t*)(ws + 72351744ull);           // 10,485,760
  ushort_t* Bsl2  = (ushort_t*)(ws + 82837504ull);           //     655,360

  // 1) exact Poisson spike train (bit-packed)
  spikegen<<<dim3(Bsz * Tst * FW / 256), dim3(256), 0, stream>>>(x, sbits);

  // 2) weight slice decomposition
  wslice<<<dim3(512 * 2048 / 256), dim3(256), 0, stream>>>(W1, 512, 2000, 2048, Bsl1);
  wslice<<<dim3(128 * 512 / 256),  dim3(256), 0, stream>>>(W2, 128, 512, 512, Bsl2);

  // 3) layer 1 in 16 chunks of 5120 rows (256 batches)
  for (int c = 0; c < 16; ++c) {
    expand_bits<<<dim3(C1_ROWS * 256 / 256), dim3(256), 0, stream>>>(
        sbits, FW, c * C1_ROWS, 2048, C1_ROWS, Abf);
    gemm5<512, 2048><<<dim3(C1_ROWS / 64, 8), dim3(320), 0, stream>>>(Abf, Bsl1, b1, inp);
    lif1<<<dim3(C1_ROWS / Tst), dim3(H1), 0, stream>>>(inp, spk1, c * (C1_ROWS / Tst));
  }

  // 4) layer 2 in 4 chunks of 20480 rows (1024 batches)
  for (int c = 0; c < 4; ++c) {
    expand_bits<<<dim3(C2_ROWS * 64 / 256), dim3(256), 0, stream>>>(
        spk1, H1 / 32, c * C2_ROWS, 512, C2_ROWS, Abf);
    gemm5<128, 512><<<dim3(C2_ROWS / 64, 2), dim3(320), 0, stream>>>(Abf, Bsl2, b2, inp);
    lif2<<<dim3(C2_ROWS / Tst), dim3(H2), 0, stream>>>(inp, mem2, c * (C2_ROWS / Tst));
  }

  // 5) readout
  finalk<<<dim3((Bsz * NOUT + 255) / 256), dim3(256), 0, stream>>>(mem2, Wd, bd, out);
}